// Round 2
// baseline (1026.892 us; speedup 1.0000x reference)
//
#include <hip/hip_runtime.h>
#include <hip/hip_bf16.h>
#include <math.h>

#define N_ROWS 16384
#define D_DIM  256
#define SPLIT  8
#define BM     64              // v1 rows per block (4 waves x 16)
#define CPB    (N_ROWS / SPLIT) // columns per block = 2048

typedef __bf16 bf16_t;
typedef __bf16 bf16x8 __attribute__((ext_vector_type(8)));
typedef __bf16 bf16x4 __attribute__((ext_vector_type(4)));
typedef float  f32x4  __attribute__((ext_vector_type(4)));

// ---------------- Kernel 1: L2-normalize rows, cast to bf16 ----------------
// One wave (64 lanes) per row; lane handles 4 consecutive floats (float4).
// 1/TEMPERATURE = 10 folded into view1's normalized output.
__global__ __launch_bounds__(256) void normalize_kernel(
    const float* __restrict__ v1, const float* __restrict__ v2,
    bf16_t* __restrict__ v1n, bf16_t* __restrict__ v2n, int n)
{
    int tid  = blockIdx.x * 256 + threadIdx.x;
    int wave = tid >> 6;
    int lane = tid & 63;
    if (wave >= 2 * n) return;
    const float* src; bf16_t* dst; float extra; int row;
    if (wave < n) { row = wave;     src = v1; dst = v1n; extra = 10.0f; }
    else          { row = wave - n; src = v2; dst = v2n; extra = 1.0f;  }
    const float4 v = *reinterpret_cast<const float4*>(src + (size_t)row * D_DIM + lane * 4);
    float ss = v.x * v.x + v.y * v.y + v.z * v.z + v.w * v.w;
    #pragma unroll
    for (int off = 1; off < 64; off <<= 1) ss += __shfl_xor(ss, off);
    float inv = extra / fmaxf(sqrtf(ss), 1e-12f);
    bf16x4 o;
    o[0] = (bf16_t)(v.x * inv);
    o[1] = (bf16_t)(v.y * inv);
    o[2] = (bf16_t)(v.z * inv);
    o[3] = (bf16_t)(v.w * inv);
    *reinterpret_cast<bf16x4*>(dst + (size_t)row * D_DIM + lane * 4) = o;
}

// ---------------- Kernel 2: logits tiles + online per-row logsumexp --------
// Swapped-operand MFMA: D = A(v2 tile) * B(v1 tile) so that C/D col (=lane&15)
// indexes the v1 row -> each lane's 4 accum values all belong to ONE v1 row.
// Online (m, s) is purely per-lane; 4-lane merge (xor 16, 32) at the end.
__global__ __launch_bounds__(256) void logits_kernel(
    const bf16_t* __restrict__ v1n, const bf16_t* __restrict__ v2n,
    float* __restrict__ pos, float2* __restrict__ partials)
{
    const int w    = threadIdx.x >> 6;
    const int lane = threadIdx.x & 63;
    const int lo   = lane & 15;
    const int hi   = lane >> 4;
    const int r0   = blockIdx.x * BM + w * 16;
    const int myrow = r0 + lo;

    // v1 fragments (B operand): lane holds B[k][col=lo] for k = kk*32 + hi*8 + j
    bf16x8 bfrag[8];
    const bf16_t* v1p = v1n + (size_t)myrow * D_DIM + hi * 8;
    #pragma unroll
    for (int kk = 0; kk < 8; ++kk)
        bfrag[kk] = *reinterpret_cast<const bf16x8*>(v1p + kk * 32);

    float m = -INFINITY, s = 0.0f;
    const int cbase = blockIdx.y * CPB;

    for (int t = 0; t < CPB / 16; ++t) {
        const int c0 = cbase + t * 16;
        const bf16_t* v2p = v2n + (size_t)(c0 + lo) * D_DIM + hi * 8;
        f32x4 acc = {0.f, 0.f, 0.f, 0.f};
        #pragma unroll
        for (int kk = 0; kk < 8; ++kk) {
            bf16x8 afrag = *reinterpret_cast<const bf16x8*>(v2p + kk * 32);
            acc = __builtin_amdgcn_mfma_f32_16x16x32_bf16(afrag, bfrag[kk], acc, 0, 0, 0);
        }
        // lane holds logits[myrow][c0 + hi*4 + r], r = 0..3 (already x10)
        const float a0 = acc[0], a1 = acc[1], a2 = acc[2], a3 = acc[3];
        const int colb = c0 + hi * 4;
        const int dr = myrow - colb;
        if (dr >= 0 && dr < 4) {  // diagonal element lives in this lane
            float dv = (dr == 0) ? a0 : (dr == 1) ? a1 : (dr == 2) ? a2 : a3;
            pos[myrow] = dv;
        }
        float tm = fmaxf(fmaxf(a0, a1), fmaxf(a2, a3));
        float mn = fmaxf(m, tm);
        s = s * __expf(m - mn)
            + __expf(a0 - mn) + __expf(a1 - mn)
            + __expf(a2 - mn) + __expf(a3 - mn);
        m = mn;
    }

    // merge the 4 lanes (same lo, hi = 0..3) holding this row
    #pragma unroll
    for (int off = 16; off <= 32; off <<= 1) {
        float om = __shfl_xor(m, off);
        float os = __shfl_xor(s, off);
        float mn = fmaxf(m, om);
        s = s * __expf(m - mn) + os * __expf(om - mn);
        m = mn;
    }
    if (lane < 16)
        partials[(size_t)myrow * SPLIT + blockIdx.y] = make_float2(m, s);
}

// ---------------- Kernel 3a: per-row loss + per-block partial sum ----------
__global__ __launch_bounds__(256) void row_loss_kernel(
    const float* __restrict__ pos, const float2* __restrict__ partials,
    float* __restrict__ bsum)
{
    const int row = blockIdx.x * 256 + threadIdx.x;
    float m = -INFINITY, s = 0.f;
    #pragma unroll
    for (int p = 0; p < SPLIT; ++p) {
        float2 ms = partials[(size_t)row * SPLIT + p];
        float mn = fmaxf(m, ms.x);
        s = s * __expf(m - mn) + ms.y * __expf(ms.x - mn);
        m = mn;
    }
    float loss = -pos[row] + m + logf(s);
    #pragma unroll
    for (int off = 1; off < 64; off <<= 1) loss += __shfl_xor(loss, off);
    __shared__ float ws4[4];
    if ((threadIdx.x & 63) == 0) ws4[threadIdx.x >> 6] = loss;
    __syncthreads();
    if (threadIdx.x == 0)
        bsum[blockIdx.x] = ws4[0] + ws4[1] + ws4[2] + ws4[3];
}

// ---------------- Kernel 3b: final mean ------------------------------------
__global__ void final_kernel(const float* __restrict__ bsum,
                             float* __restrict__ out, int nb, float invn)
{
    float v = (threadIdx.x < nb) ? bsum[threadIdx.x] : 0.f;
    #pragma unroll
    for (int off = 1; off < 64; off <<= 1) v += __shfl_xor(v, off);
    if (threadIdx.x == 0) out[0] = v * invn;
}

extern "C" void kernel_launch(void* const* d_in, const int* in_sizes, int n_in,
                              void* d_out, int out_size, void* d_ws, size_t ws_size,
                              hipStream_t stream)
{
    const float* view1 = (const float*)d_in[0];
    const float* view2 = (const float*)d_in[1];
    float* out = (float*)d_out;
    const int n = in_sizes[0] / D_DIM;   // 16384

    char* ws = (char*)d_ws;
    bf16_t* v1n = (bf16_t*)ws;                                    // 8 MB
    bf16_t* v2n = (bf16_t*)(ws + (size_t)n * D_DIM * 2);          // 8 MB
    char*   p2  = ws + (size_t)n * D_DIM * 4;
    float*  pos = (float*)p2;                                     // 64 KB
    float2* partials = (float2*)(p2 + (size_t)n * 4);             // 1 MB
    float*  bsum = (float*)(p2 + (size_t)n * 4 + (size_t)n * SPLIT * 8); // 256 B

    // 1) normalize -> bf16 (2n rows, one wave each, 4 waves/block)
    normalize_kernel<<<(2 * n) / 4, 256, 0, stream>>>(view1, view2, v1n, v2n, n);

    // 2) tiled logits + online logsumexp partials
    dim3 grid2(n / BM, SPLIT, 1);
    logits_kernel<<<grid2, 256, 0, stream>>>(v1n, v2n, pos, partials);

    // 3) reduce
    row_loss_kernel<<<n / 256, 256, 0, stream>>>(pos, partials, bsum);
    final_kernel<<<1, 64, 0, stream>>>(bsum, out, n / 256, 1.0f / (float)n);
}

// Round 4
// 195.903 us; speedup vs baseline: 5.2418x; 5.2418x over previous
//
#include <hip/hip_runtime.h>
#include <hip/hip_bf16.h>
#include <math.h>

#define N_ROWS 16384
#define D_DIM  256
#define SPLIT  8
#define G      4                 // row-groups (of 16) per wave
#define BM     256               // v1 rows per block = 4 waves * G * 16
#define CPB    (N_ROWS / SPLIT)  // columns swept per block = 2048
#define LOGIT_MAX 10.0f          // logits = 10*cosine <= 10 -> fixed LSE max

typedef __bf16 bf16_t;
typedef __bf16 bf16x8 __attribute__((ext_vector_type(8)));
typedef __bf16 bf16x4 __attribute__((ext_vector_type(4)));
typedef float  f32x4  __attribute__((ext_vector_type(4)));

// ---------------- Kernel 1: L2-normalize rows, cast to bf16 ----------------
// One wave per row; lane handles 4 consecutive floats. 1/T=10 folded into v1.
__global__ __launch_bounds__(256) void normalize_kernel(
    const float* __restrict__ v1, const float* __restrict__ v2,
    bf16_t* __restrict__ v1n, bf16_t* __restrict__ v2n, int n)
{
    int tid  = blockIdx.x * 256 + threadIdx.x;
    int wave = tid >> 6;
    int lane = tid & 63;
    if (wave >= 2 * n) return;
    const float* src; bf16_t* dst; float extra; int row;
    if (wave < n) { row = wave;     src = v1; dst = v1n; extra = 10.0f; }
    else          { row = wave - n; src = v2; dst = v2n; extra = 1.0f;  }
    const float4 v = *reinterpret_cast<const float4*>(src + (size_t)row * D_DIM + lane * 4);
    float ss = v.x * v.x + v.y * v.y + v.z * v.z + v.w * v.w;
    #pragma unroll
    for (int off = 1; off < 64; off <<= 1) ss += __shfl_xor(ss, off);
    float inv = extra / fmaxf(sqrtf(ss), 1e-12f);
    bf16x4 o;
    o[0] = (bf16_t)(v.x * inv);
    o[1] = (bf16_t)(v.y * inv);
    o[2] = (bf16_t)(v.z * inv);
    o[3] = (bf16_t)(v.w * inv);
    *reinterpret_cast<bf16x4*>(dst + (size_t)row * D_DIM + lane * 4) = o;
}

// ---------------- Kernel 2: logits + fixed-max row sumexp ------------------
// Swapped-operand MFMA: D = A(v2 tile) * B(v1 frag); D col (=lane&15) indexes
// the v1 row, so each lane's 4 acc values belong to ONE v1 row. G=4 row-groups
// per wave amortize the v2-tile traffic 4x. v2 tile (16 rows x 256 = 8KB) is
// staged once per block into LDS via global_load_lds (dest linear, source
// pre-XOR-swizzled; ds_read applies the same XOR -> conflict-minimal b128).
__global__ __launch_bounds__(256, 2) void logits_kernel(
    const bf16_t* __restrict__ v1n, const bf16_t* __restrict__ v2n,
    float* __restrict__ pos, float* __restrict__ partials)
{
    __shared__ bf16_t lds[2][4096];   // 2 x 8KB: [16 rows][256 bf16] linear

    const int tid  = threadIdx.x;
    const int w    = tid >> 6;
    const int lane = tid & 63;
    const int lo   = lane & 15;
    const int hi   = lane >> 4;
    const int xr   = lo & 7;                 // read-side XOR key
    const int r0w  = blockIdx.x * BM + w * (G * 16);

    // v1 fragments, register-resident for the whole sweep: [group][kk]
    bf16x8 bfrag[G][8];
    #pragma unroll
    for (int g = 0; g < G; ++g) {
        const bf16_t* v1p = v1n + (size_t)(r0w + g * 16 + lo) * D_DIM + hi * 8;
        #pragma unroll
        for (int kk = 0; kk < 8; ++kk)
            bfrag[g][kk] = *reinterpret_cast<const bf16x8*>(v1p + kk * 32);
    }

    const int cbase = blockIdx.y * CPB;
    float s[G] = {0.f, 0.f, 0.f, 0.f};

    // ---- stage tile 0 into buf 0 (source address pre-swizzled) ----
    {
        #pragma unroll
        for (int j = 0; j < 2; ++j) {
            int r  = j * 8 + (tid >> 5);            // tile row 0..15
            int ch = (tid & 31) ^ (r & 7);          // swizzled 16B-chunk
            const bf16_t* g = v2n + (size_t)(cbase + r) * D_DIM + ch * 8;
            __builtin_amdgcn_global_load_lds(
                (const __attribute__((address_space(1))) unsigned int*)g,
                (__attribute__((address_space(3))) unsigned int*)(&lds[0][0] + j * 2048 + w * 512),
                16, 0, 0);
        }
    }

    const int NT = CPB / 16;   // 128 tiles
    int cur = 0;
    for (int t = 0; t < NT; ++t) {
        asm volatile("s_waitcnt vmcnt(0)" ::: "memory");
        __builtin_amdgcn_s_barrier();
        asm volatile("" ::: "memory");

        // issue next tile's stage into the other buffer (in flight during MFMA)
        if (t + 1 < NT) {
            const int c0n = cbase + (t + 1) * 16;
            #pragma unroll
            for (int j = 0; j < 2; ++j) {
                int r  = j * 8 + (tid >> 5);
                int ch = (tid & 31) ^ (r & 7);
                const bf16_t* g = v2n + (size_t)(c0n + r) * D_DIM + ch * 8;
                __builtin_amdgcn_global_load_lds(
                    (const __attribute__((address_space(1))) unsigned int*)g,
                    (__attribute__((address_space(3))) unsigned int*)(&lds[cur ^ 1][0] + j * 2048 + w * 512),
                    16, 0, 0);
            }
        }

        const bf16_t* bufr = &lds[cur][0];
        f32x4 acc[G];
        #pragma unroll
        for (int g = 0; g < G; ++g) acc[g] = (f32x4){0.f, 0.f, 0.f, 0.f};

        #pragma unroll
        for (int kk = 0; kk < 8; ++kk) {
            const int q = hi + 4 * kk;               // 16B-chunk index in row
            const bf16x8 a = *reinterpret_cast<const bf16x8*>(
                bufr + lo * 256 + ((q ^ xr) << 3));  // swizzled ds_read_b128
            #pragma unroll
            for (int g = 0; g < G; ++g)
                acc[g] = __builtin_amdgcn_mfma_f32_16x16x32_bf16(a, bfrag[g][kk], acc[g], 0, 0, 0);
        }

        const int colb = cbase + t * 16 + hi * 4;
        #pragma unroll
        for (int g = 0; g < G; ++g) {
            const float a0 = acc[g][0], a1 = acc[g][1], a2 = acc[g][2], a3 = acc[g][3];
            const int myrow = r0w + g * 16 + lo;
            const int dr = myrow - colb;
            if (dr >= 0 && dr < 4) {                 // diagonal lives here
                float dv = (dr == 0) ? a0 : (dr == 1) ? a1 : (dr == 2) ? a2 : a3;
                pos[myrow] = dv;
            }
            s[g] += __expf(a0 - LOGIT_MAX) + __expf(a1 - LOGIT_MAX)
                  + __expf(a2 - LOGIT_MAX) + __expf(a3 - LOGIT_MAX);
        }

        asm volatile("" ::: "memory");
        __builtin_amdgcn_s_barrier();
        cur ^= 1;
    }

    // merge the 4 hi-lanes holding each row, write split partial
    #pragma unroll
    for (int g = 0; g < G; ++g) {
        float v = s[g];
        v += __shfl_xor(v, 16);
        v += __shfl_xor(v, 32);
        if (lane < 16)
            partials[(size_t)(r0w + g * 16 + lo) * SPLIT + blockIdx.y] = v;
    }
}

// ---------------- Kernel 3a: per-row loss + per-block partial sum ----------
__global__ __launch_bounds__(256) void row_loss_kernel(
    const float* __restrict__ pos, const float* __restrict__ partials,
    float* __restrict__ bsum)
{
    const int row = blockIdx.x * 256 + threadIdx.x;
    float ssum = 0.f;
    #pragma unroll
    for (int p = 0; p < SPLIT; ++p)
        ssum += partials[(size_t)row * SPLIT + p];
    float loss = -pos[row] + LOGIT_MAX + logf(ssum);
    #pragma unroll
    for (int off = 1; off < 64; off <<= 1) loss += __shfl_xor(loss, off);
    __shared__ float ws4[4];
    if ((threadIdx.x & 63) == 0) ws4[threadIdx.x >> 6] = loss;
    __syncthreads();
    if (threadIdx.x == 0)
        bsum[blockIdx.x] = ws4[0] + ws4[1] + ws4[2] + ws4[3];
}

// ---------------- Kernel 3b: final mean ------------------------------------
__global__ void final_kernel(const float* __restrict__ bsum,
                             float* __restrict__ out, int nb, float invn)
{
    float v = (threadIdx.x < nb) ? bsum[threadIdx.x] : 0.f;
    #pragma unroll
    for (int off = 1; off < 64; off <<= 1) v += __shfl_xor(v, off);
    if (threadIdx.x == 0) out[0] = v * invn;
}

extern "C" void kernel_launch(void* const* d_in, const int* in_sizes, int n_in,
                              void* d_out, int out_size, void* d_ws, size_t ws_size,
                              hipStream_t stream)
{
    const float* view1 = (const float*)d_in[0];
    const float* view2 = (const float*)d_in[1];
    float* out = (float*)d_out;
    const int n = in_sizes[0] / D_DIM;   // 16384

    char* ws = (char*)d_ws;
    bf16_t* v1n = (bf16_t*)ws;                                    // 8 MB
    bf16_t* v2n = (bf16_t*)(ws + (size_t)n * D_DIM * 2);          // 8 MB
    char*   p2  = ws + (size_t)n * D_DIM * 4;
    float*  pos = (float*)p2;                                     // 64 KB
    float*  partials = (float*)(p2 + (size_t)n * 4);              // 512 KB
    float*  bsum = (float*)(p2 + (size_t)n * 4 + (size_t)n * SPLIT * 4); // 256 B

    // 1) normalize -> bf16
    normalize_kernel<<<(2 * n) / 4, 256, 0, stream>>>(view1, view2, v1n, v2n, n);

    // 2) tiled logits + fixed-max sumexp partials
    dim3 grid2(n / BM, SPLIT, 1);
    logits_kernel<<<grid2, 256, 0, stream>>>(v1n, v2n, pos, partials);

    // 3) reduce
    row_loss_kernel<<<n / 256, 256, 0, stream>>>(pos, partials, bsum);
    final_kernel<<<1, 64, 0, stream>>>(bsum, out, n / 256, 1.0f / (float)n);
}